// Round 3
// baseline (89.235 us; speedup 1.0000x reference)
//
#include <hip/hip_runtime.h>
#include <math.h>

// Problem constants
#define Nn   8192
#define DXc  64
#define DZc  128
#define DYc  16
#define Hc   512
#define KCp  672    // padded concat K: 512 (H) + 128 (z) + 16 (y) + 16 zeros
#define SSTR 520    // LDS S row stride (bf16): 1040 B -> 16B-aligned, 4-bank rotation/row

typedef short bf16x8 __attribute__((ext_vector_type(8)));   // 8 bf16 = 4 VGPRs
typedef float f32x4  __attribute__((ext_vector_type(4)));

__device__ __forceinline__ float fast_tanh(float x) {
    float e = __expf(2.0f * x);
    return 1.0f - 2.0f / (e + 1.0f);
}
__device__ __forceinline__ short f2bf(float f) {            // fp32 -> bf16 RNE
    unsigned u = __float_as_uint(f);
    return (short)((u + 0x7FFFu + ((u >> 16) & 1u)) >> 16);
}
__device__ __forceinline__ bf16x8 pack8(float4 a, float4 b) {
    bf16x8 r;
    r[0]=f2bf(a.x); r[1]=f2bf(a.y); r[2]=f2bf(a.z); r[3]=f2bf(a.w);
    r[4]=f2bf(b.x); r[5]=f2bf(b.y); r[6]=f2bf(b.z); r[7]=f2bf(b.w);
    return r;
}

// ---- prep: all-coalesced weight repack ----
// blocks 0..7  : W1T[j][k] = bf16(W1[k][j])          (LDS-tiled transpose, 64 j/block)
// blocks 8..15 : WcT[z][k<512] = bf16(W2[k][z])      (LDS-tiled transpose, 64 k/block)
// blocks 16..23: WcT[z][512+c] = bf16(-A[z][c])      (direct, coalesced)
// block  24    : WcT[z][640+c] = bf16(-B[z][c]) / 0  (direct + zero pad)
__global__ void prep_kernel(const float* __restrict__ W1,
                            const float* __restrict__ W2,
                            const float* __restrict__ A,
                            const float* __restrict__ Bm,
                            short* __restrict__ W1T,
                            short* __restrict__ WcT) {
    __shared__ float tile[64 * 129];     // 33 KB, reused by both transpose parts
    const int blk = blockIdx.x, t = threadIdx.x;

    if (blk < 8) {                       // W1 transpose: j-tile [64*blk, +64), k = 0..63
        const int jb = blk * 64;
#pragma unroll
        for (int p = 0; p < 16; p++) {
            int lin = p * 256 + t;
            int k = lin >> 6, jj = lin & 63;
            tile[jj * 65 + k] = W1[(size_t)k * Hc + jb + jj];   // coalesced read
        }
        __syncthreads();
#pragma unroll
        for (int p = 0; p < 2; p++) {
            int jj = p * 32 + (t >> 3), k8 = (t & 7) * 8;
            bf16x8 v;
#pragma unroll
            for (int i = 0; i < 8; i++) v[i] = f2bf(tile[jj * 65 + k8 + i]);
            *(bf16x8*)(W1T + (size_t)(jb + jj) * DXc + k8) = v;  // coalesced write
        }
    } else if (blk < 16) {               // W2 transpose: k-tile [64*(blk-8), +64), z = 0..127
        const int kb = (blk - 8) * 64;
#pragma unroll
        for (int p = 0; p < 32; p++) {
            int lin = p * 256 + t;
            int kk = lin >> 7, z = lin & 127;
            tile[kk * 129 + z] = W2[(size_t)(kb + kk) * DZc + z];  // coalesced read
        }
        __syncthreads();
#pragma unroll
        for (int p = 0; p < 4; p++) {
            int z = p * 32 + (t >> 3), k8 = (t & 7) * 8;
            bf16x8 v;
#pragma unroll
            for (int i = 0; i < 8; i++) v[i] = f2bf(tile[(k8 + i) * 129 + z]);
            *(bf16x8*)(WcT + (size_t)z * KCp + kb + k8) = v;     // coalesced write
        }
    } else if (blk < 24) {               // -A^T rows: direct (A is z-major like WcT here)
        int idx8 = (blk - 16) * 256 + t;           // 2048 chunks of 8
        int z = idx8 >> 4, c8 = (idx8 & 15) * 8;
        float4 a0 = *(const float4*)(A + (size_t)z * DZc + c8);
        float4 a1 = *(const float4*)(A + (size_t)z * DZc + c8 + 4);
        bf16x8 v;
        v[0]=f2bf(-a0.x); v[1]=f2bf(-a0.y); v[2]=f2bf(-a0.z); v[3]=f2bf(-a0.w);
        v[4]=f2bf(-a1.x); v[5]=f2bf(-a1.y); v[6]=f2bf(-a1.z); v[7]=f2bf(-a1.w);
        *(bf16x8*)(WcT + (size_t)z * KCp + Hc + c8) = v;
    } else {                             // -B^T rows + zero pad: 128 z x 32 k-slots
#pragma unroll
        for (int p = 0; p < 2; p++) {
            int cid = p * 256 + t;                 // 512 chunks of 8
            int z = cid >> 2, c8 = (cid & 3) * 8;
            bf16x8 v = (bf16x8){0,0,0,0,0,0,0,0};
            if (c8 < DYc) {
                float4 b0 = *(const float4*)(Bm + (size_t)z * DYc + c8);
                float4 b1 = *(const float4*)(Bm + (size_t)z * DYc + c8 + 4);
                v[0]=f2bf(-b0.x); v[1]=f2bf(-b0.y); v[2]=f2bf(-b0.z); v[3]=f2bf(-b0.w);
                v[4]=f2bf(-b1.x); v[5]=f2bf(-b1.y); v[6]=f2bf(-b1.z); v[7]=f2bf(-b1.w);
            }
            *(bf16x8*)(WcT + (size_t)z * KCp + Hc + DZc + c8) = v;
        }
    }
}

#define MFMA16(a, b, c) __builtin_amdgcn_mfma_f32_16x16x32_bf16((a), (b), (c), 0, 0, 0)

// ---- main: 16 samples/block; phase B K-split across waves, phase C z-split ----
__global__ __launch_bounds__(256, 2)
void pde_main(const float* __restrict__ z_pred,
              const float* __restrict__ x_label,
              const float* __restrict__ y_label,
              const float* __restrict__ b1,
              const short* __restrict__ W1T,
              const short* __restrict__ WcT,
              float* __restrict__ partial) {
    __shared__ __align__(16) short sS[16 * SSTR];   // S tile: 16 samples x 512 j (bf16)
    __shared__ float rsum[16];

    const int tid  = threadIdx.x;
    const int w    = tid >> 6;
    const int lane = tid & 63;
    const int n16  = lane & 15;       // A-row (sample) / B-row select
    const int q    = lane >> 4;       // quad: k-subchunk
    const int n0   = blockIdx.x * 16;

    if (tid < 16) rsum[tid] = 0.f;

    // --- x / tanh(x) A-fragments: A[m=n16][k=q*8+i], k-chunks {0..31},{32..63} ---
    const float* xp = x_label + (size_t)(n0 + n16) * DXc + q * 8;
    float4 x0 = *(const float4*)xp,        x1 = *(const float4*)(xp + 4);
    float4 x2 = *(const float4*)(xp + 32), x3 = *(const float4*)(xp + 36);
    bf16x8 ax0 = pack8(x0, x1), ax1 = pack8(x2, x3);
    bf16x8 at0, at1;
    {
        float v[16] = {x0.x,x0.y,x0.z,x0.w, x1.x,x1.y,x1.z,x1.w,
                       x2.x,x2.y,x2.z,x2.w, x3.x,x3.y,x3.z,x3.w};
#pragma unroll
        for (int i = 0; i < 8; i++) { at0[i] = f2bf(fast_tanh(v[i])); at1[i] = f2bf(fast_tanh(v[8 + i])); }
    }

    // --- phase B: wave w builds S columns j = [w*128, w*128+128) ---
#pragma unroll
    for (int cc = 0; cc < 2; cc++) {
        const int jb = w * 128 + cc * 64;
#pragma unroll
        for (int t = 0; t < 4; t++) {
            const int jt = jb + t * 16;
            const short* bp = W1T + (size_t)(jt + n16) * DXc + q * 8;
            bf16x8 bw0 = *(const bf16x8*)bp;
            bf16x8 bw1 = *(const bf16x8*)(bp + 32);
            f32x4 h = (f32x4){0.f,0.f,0.f,0.f};
            f32x4 u = (f32x4){0.f,0.f,0.f,0.f};
            h = MFMA16(ax0, bw0, h);  h = MFMA16(ax1, bw1, h);
            u = MFMA16(at0, bw0, u);  u = MFMA16(at1, bw1, u);
            const float bj = b1[jt + n16];            // C col = n16 -> j
#pragma unroll
            for (int reg = 0; reg < 4; reg++) {       // C row = q*4+reg -> sample
                float tv = fast_tanh(h[reg] + bj);
                float s  = (1.f - tv * tv) * u[reg];
                sS[(q * 4 + reg) * SSTR + jt + n16] = f2bf(s);
            }
        }
    }

    // --- corrections (independent of S -> before barrier): wave w owns z cols [32w,32w+32) ---
    const int z0r = w * 32;
    const short* wr0 = WcT + (size_t)(z0r + n16) * KCp;        // B rows for zt = 2w
    const short* wr1 = WcT + (size_t)(z0r + 16 + n16) * KCp;   // B rows for zt = 2w+1
    f32x4 acc0 = (f32x4){0.f,0.f,0.f,0.f};
    f32x4 acc1 = (f32x4){0.f,0.f,0.f,0.f};

    {   // z_pred @ (-A^T): K = 512..639
        const float* zp = z_pred + (size_t)(n0 + n16) * DZc + q * 8;
#pragma unroll
        for (int kc = 0; kc < 4; kc++) {
            float4 a0 = *(const float4*)(zp + kc * 32);
            float4 a1 = *(const float4*)(zp + kc * 32 + 4);
            bf16x8 az = pack8(a0, a1);
            bf16x8 b0 = *(const bf16x8*)(wr0 + Hc + kc * 32 + q * 8);
            bf16x8 b1f = *(const bf16x8*)(wr1 + Hc + kc * 32 + q * 8);
            acc0 = MFMA16(az, b0, acc0);
            acc1 = MFMA16(az, b1f, acc1);
        }
    }
    {   // y @ (-B^T): K = 640..671 (real 640..655, rest zero both sides)
        bf16x8 ay = (bf16x8){0,0,0,0,0,0,0,0};
        if (q < 2) {
            const float* yp = y_label + (size_t)(n0 + n16) * DYc + q * 8;
            float4 y0 = *(const float4*)yp, y1 = *(const float4*)(yp + 4);
            ay = pack8(y0, y1);
        }
        bf16x8 b0 = *(const bf16x8*)(wr0 + Hc + DZc + q * 8);
        bf16x8 b1f = *(const bf16x8*)(wr1 + Hc + DZc + q * 8);
        acc0 = MFMA16(ay, b0, acc0);
        acc1 = MFMA16(ay, b1f, acc1);
    }

    __syncthreads();

    // --- phase C: full-K S @ Wc for this wave's 32 z columns ---
#pragma unroll
    for (int kc = 0; kc < 16; kc++) {
        bf16x8 sa = *(const bf16x8*)(sS + n16 * SSTR + kc * 32 + q * 8);
        bf16x8 b0 = *(const bf16x8*)(wr0 + kc * 32 + q * 8);
        bf16x8 b1f = *(const bf16x8*)(wr1 + kc * 32 + q * 8);
        acc0 = MFMA16(sa, b0, acc0);
        acc1 = MFMA16(sa, b1f, acc1);
    }

    // --- epilogue: per-row sum of squares, cross-lane + cross-wave reduce ---
    float ss[4];
#pragma unroll
    for (int reg = 0; reg < 4; reg++) {
        ss[reg] = fmaf(acc0[reg], acc0[reg], acc1[reg] * acc1[reg]);
        ss[reg] += __shfl_xor(ss[reg], 1);
        ss[reg] += __shfl_xor(ss[reg], 2);
        ss[reg] += __shfl_xor(ss[reg], 4);
        ss[reg] += __shfl_xor(ss[reg], 8);
    }
    if (n16 == 0) {
#pragma unroll
        for (int reg = 0; reg < 4; reg++) atomicAdd(&rsum[q * 4 + reg], ss[reg]);
    }
    __syncthreads();

    if (tid == 0) {
        float s = 0.f;
#pragma unroll
        for (int i = 0; i < 16; i++) s += sqrtf(rsum[i]);
        partial[blockIdx.x] = s;
    }
}

// ---- final: 512 block partials -> mean ----
__global__ void reduce_kernel(const float* __restrict__ partial, float* __restrict__ out) {
    __shared__ float s4[4];
    int tid = threadIdx.x;
    float v = partial[tid] + partial[tid + 256];
#pragma unroll
    for (int off = 32; off >= 1; off >>= 1) v += __shfl_down(v, off);
    if ((tid & 63) == 0) s4[tid >> 6] = v;
    __syncthreads();
    if (tid == 0) out[0] = (s4[0] + s4[1] + s4[2] + s4[3]) * (1.0f / (float)Nn);
}

extern "C" void kernel_launch(void* const* d_in, const int* in_sizes, int n_in,
                              void* d_out, int out_size, void* d_ws, size_t ws_size,
                              hipStream_t stream) {
    const float* z_pred  = (const float*)d_in[0];
    const float* x_label = (const float*)d_in[1];
    const float* y_label = (const float*)d_in[2];
    const float* W1      = (const float*)d_in[3];
    const float* b1      = (const float*)d_in[4];
    const float* W2      = (const float*)d_in[5];
    // d_in[6] = b2: cancels in the Jacobian-vector product
    const float* A       = (const float*)d_in[7];
    const float* Bm      = (const float*)d_in[8];

    short* W1T = (short*)d_ws;                       // 512*64 bf16  = 64 KB
    short* WcT = W1T + Hc * DXc;                     // 128*672 bf16 = 168 KB
    float* partial = (float*)(WcT + DZc * KCp);      // 512 floats

    prep_kernel<<<25, 256, 0, stream>>>(W1, W2, A, Bm, W1T, WcT);
    pde_main<<<Nn / 16, 256, 0, stream>>>(z_pred, x_label, y_label, b1, W1T, WcT, partial);
    reduce_kernel<<<1, 256, 0, stream>>>(partial, (float*)d_out);
}